// Round 5
// baseline (335.061 us; speedup 1.0000x reference)
//
#include <hip/hip_runtime.h>
#include <hip/hip_bf16.h>
#include <hip/hip_cooperative_groups.h>

namespace cg = cooperative_groups;

// B=32, C=128, L=256, K=2. deg==1 -> L_t = -adj.
// out = relu( x@Th0 - adjT@(x@Th1) )
// ONE cooperative kernel, 512 blocks x 256 threads, phases separated by grid.sync():
//  A: pairdist(i<=j) + x->bf16 + Theta^T + a^T   (2212 jobs)
//  B1: rnorm (batch L2 norm reciprocal)          (64 blocks)
//  B2: adjacency (softmax-normalized, bf16, transposed)
//  C: xTh = x_flat[4096,256] @ ThT  (bf16 MFMA, LDS-swizzled B)
//  D: out = relu(xTh0 - adjT@xTh1)  (batched MFMA, fused epilogue)

#define NB 32
#define NC 128
#define NL 256
#define GRID 512

typedef short bf16x8 __attribute__((ext_vector_type(8)));
typedef float f32x4 __attribute__((ext_vector_type(4)));

static __device__ __forceinline__ unsigned short f2bf(float f) {
    unsigned u = __builtin_bit_cast(unsigned, f);
    u += 0x7fff + ((u >> 16) & 1);            // RNE
    return (unsigned short)(u >> 16);
}

__device__ const unsigned char TI36[36] = {0,0,0,0,0,0,0,0, 1,1,1,1,1,1,1, 2,2,2,2,2,2,
                                           3,3,3,3,3, 4,4,4,4, 5,5,5, 6,6, 7};
__device__ const unsigned char TJ36[36] = {0,1,2,3,4,5,6,7, 1,2,3,4,5,6,7, 2,3,4,5,6,7,
                                           3,4,5,6,7, 4,5,6,7, 5,6,7, 6,7, 7};

__global__ __launch_bounds__(256, 2) void k_fused(
    const float* __restrict__ x, const float* __restrict__ Theta, const float* __restrict__ a,
    float* __restrict__ diff, unsigned short* __restrict__ xb, unsigned short* __restrict__ thT,
    float* __restrict__ aT, float* __restrict__ rnorm, unsigned short* __restrict__ adjTb,
    float* __restrict__ xTh0, unsigned short* __restrict__ xTh1T, float* __restrict__ out)
{
    cg::grid_group grid = cg::this_grid();
    __shared__ __align__(16) float smem[4496];   // 17984 B: pairdist xi|xj|sT, transpose [64][65], Bs 16KB
    __shared__ float partial[4];
    int bid = blockIdx.x, tid = threadIdx.x;

    // ================= Phase A: pairdist + conversions/transposes =================
    for (int job = bid; job < 2212; job += GRID) {
        if (job < 1152) {
            int b = job / 36, p = job - b * 36;
            int i0 = TI36[p] * 16, j0 = TJ36[p] * 16;
            float* xi = smem;            // [16][132]
            float* xj = smem + 2112;     // [16][132]
            float* sT = smem + 4224;     // [16][17]
            const float4* x4 = (const float4*)(x + (size_t)b * NC * NL);
            int il = tid >> 4, jl = tid & 15;
            float acc = 0.f;
            #pragma unroll
            for (int h = 0; h < 2; ++h) {           // L split in halves (LDS <= 18 KB)
                __syncthreads();
                for (int idx = tid; idx < 512; idx += 256) {
                    int r = idx >> 5, c = idx & 31;
                    *(float4*)&xi[r * 132 + c * 4] = x4[(i0 + r) * 64 + h * 32 + c];
                    *(float4*)&xj[r * 132 + c * 4] = x4[(j0 + r) * 64 + h * 32 + c];
                }
                __syncthreads();
                #pragma unroll 8
                for (int l4 = 0; l4 < 32; ++l4) {
                    float4 u = *(const float4*)&xi[il * 132 + l4 * 4];
                    float4 v = *(const float4*)&xj[jl * 132 + l4 * 4];
                    acc += fabsf(u.x - v.x) + fabsf(u.y - v.y) +
                           fabsf(u.z - v.z) + fabsf(u.w - v.w);
                }
            }
            float* D = diff + (size_t)b * NC * NC;
            D[(i0 + il) * NC + j0 + jl] = acc;      // direct, coalesced
            __syncthreads();
            sT[jl * 17 + il] = acc;
            __syncthreads();
            D[(j0 + il) * NC + i0 + jl] = sT[il * 17 + jl];  // mirror via LDS transpose
        } else if (job < 2176) {
            int idx = (job - 1152) * 256 + tid;     // 262144 float4 = all of x
            float4 v = ((const float4*)x)[idx];
            ushort4 o;
            o.x = f2bf(v.x); o.y = f2bf(v.y); o.z = f2bf(v.z); o.w = f2bf(v.w);
            ((ushort4*)xb)[idx] = o;
        } else if (job < 2208) {
            // thT[t*256+n][l] = Theta[t][l][n]; 64x64 tiles
            int tt = job - 2176;
            int t = tt >> 4, rem = tt & 15;
            int l0 = (rem >> 2) * 64, n0 = (rem & 3) * 64;
            const float* Tp = Theta + (size_t)t * 65536;
            __syncthreads();
            for (int it = tid; it < 4096; it += 256) {
                int r = it >> 6, c = it & 63;
                smem[r * 65 + c] = Tp[(l0 + r) * 256 + n0 + c];
            }
            __syncthreads();
            for (int it = tid; it < 4096; it += 256) {
                int r = it >> 6, c = it & 63;       // r = n-local, c = l-local
                thT[(size_t)(t * 256 + n0 + r) * 256 + l0 + c] = f2bf(smem[c * 65 + r]);
            }
        } else {
            // aT[j][i] = a[i][j]
            int tt = job - 2208;
            int i0 = (tt >> 1) * 64, j0 = (tt & 1) * 64;
            __syncthreads();
            for (int it = tid; it < 4096; it += 256) {
                int r = it >> 6, c = it & 63;
                smem[r * 65 + c] = a[(i0 + r) * NC + j0 + c];
            }
            __syncthreads();
            for (int it = tid; it < 4096; it += 256) {
                int r = it >> 6, c = it & 63;
                aT[(j0 + r) * NC + i0 + c] = smem[c * 65 + r];
            }
        }
    }
    grid.sync();

    // ================= Phase B1: rnorm[i,j] = 1/max(||diff[:,i,j]||,1e-12) =================
    if (bid < 64) {
        int idx = bid * 256 + tid;                  // 16384 (i,j) entries
        float ss = 0.f;
        #pragma unroll
        for (int bb = 0; bb < NB; ++bb) {
            float v = diff[(size_t)bb * NC * NC + idx];
            ss = fmaf(v, v, ss);
        }
        rnorm[idx] = 1.0f / fmaxf(sqrtf(ss), 1e-12f);
    }
    grid.sync();

    // ================= Phase B2: adjacency (transposed, bf16) =================
    {
        int g = tid >> 7;          // two 128-thread groups per block
        int i = tid & 127;
        #pragma unroll
        for (int it = 0; it < 4; ++it) {
            __syncthreads();       // protect partial[] reuse
            int P = it * 1024 + bid * 2 + g;        // 4096 (b,j) pairs
            int b = P >> 7, j = P & 127;
            float d  = diff[(size_t)b * NC * NC + j * NC + i];   // symmetric read
            float rn = rnorm[j * NC + i];
            float av = aT[j * NC + i];
            float s = __expf(fmaxf((1.0f - d * rn) * av, 0.0f));
            float t = s;
            #pragma unroll
            for (int off = 32; off; off >>= 1) t += __shfl_xor(t, off);
            if ((tid & 63) == 0) partial[tid >> 6] = t;
            __syncthreads();
            float total = partial[g << 1] + partial[(g << 1) | 1];
            adjTb[(size_t)b * NC * NC + j * NC + i] = f2bf(s / total);
        }
    }
    grid.sync();

    // ================= Phase C: xTh = x_flat[4096,256] @ ThT (MFMA) =================
    {
        unsigned short* Bs = (unsigned short*)smem;  // [32][256] bf16 XOR-swizzled, 16 KB
        int mt = bid >> 4, nt = bid & 15;
        int m0 = mt * 128, n0 = nt * 32;
        int w = tid >> 6, lane = tid & 63;
        int lr = lane & 15, lg = lane >> 4;

        #pragma unroll
        for (int it = 0; it < 4; ++it) {
            int c = tid + it * 256;
            int n = c >> 5, kc = c & 31;
            bf16x8 v = *(const bf16x8*)(thT + (size_t)(n0 + n) * 256 + kc * 8);
            int dst = n * 512 + ((kc * 16) ^ ((n & 7) << 4));
            *(bf16x8*)((char*)Bs + dst) = v;
        }
        __syncthreads();

        const unsigned short* Ap0 = xb + (size_t)(m0 + w * 32 + lr) * 256 + lg * 8;
        const unsigned short* Ap1 = Ap0 + 16 * 256;
        f32x4 acc00 = {0.f,0.f,0.f,0.f}, acc01 = {0.f,0.f,0.f,0.f};
        f32x4 acc10 = {0.f,0.f,0.f,0.f}, acc11 = {0.f,0.f,0.f,0.f};
        int swz = (lr & 7) << 4;
        #pragma unroll
        for (int ks = 0; ks < 8; ++ks) {
            bf16x8 a0 = *(const bf16x8*)(Ap0 + ks * 32);
            bf16x8 a1 = *(const bf16x8*)(Ap1 + ks * 32);
            int kb = (ks * 64 + lg * 16) ^ swz;
            bf16x8 b0 = *(const bf16x8*)((char*)Bs + lr * 512 + kb);
            bf16x8 b1 = *(const bf16x8*)((char*)Bs + (16 + lr) * 512 + kb);
            acc00 = __builtin_amdgcn_mfma_f32_16x16x32_bf16(a0, b0, acc00, 0, 0, 0);
            acc01 = __builtin_amdgcn_mfma_f32_16x16x32_bf16(a0, b1, acc01, 0, 0, 0);
            acc10 = __builtin_amdgcn_mfma_f32_16x16x32_bf16(a1, b0, acc10, 0, 0, 0);
            acc11 = __builtin_amdgcn_mfma_f32_16x16x32_bf16(a1, b1, acc11, 0, 0, 0);
        }

        int ir0 = w * 32 + lg * 4;
        if (n0 < 256) {
            float* O = xTh0 + (size_t)mt * 32768 + (size_t)ir0 * 256 + n0 + lr;
            #pragma unroll
            for (int r = 0; r < 4; ++r) {
                O[r * 256]              = acc00[r];
                O[r * 256 + 16]         = acc01[r];
                O[(16 + r) * 256]       = acc10[r];
                O[(16 + r) * 256 + 16]  = acc11[r];
            }
        } else {
            int n1 = n0 - 256;
            unsigned short* O = xTh1T + (size_t)mt * 32768;
            ushort4 p;
            p.x = f2bf(acc00[0]); p.y = f2bf(acc00[1]); p.z = f2bf(acc00[2]); p.w = f2bf(acc00[3]);
            *(ushort4*)(O + (size_t)(n1 + lr) * 128 + ir0) = p;
            p.x = f2bf(acc01[0]); p.y = f2bf(acc01[1]); p.z = f2bf(acc01[2]); p.w = f2bf(acc01[3]);
            *(ushort4*)(O + (size_t)(n1 + 16 + lr) * 128 + ir0) = p;
            p.x = f2bf(acc10[0]); p.y = f2bf(acc10[1]); p.z = f2bf(acc10[2]); p.w = f2bf(acc10[3]);
            *(ushort4*)(O + (size_t)(n1 + lr) * 128 + ir0 + 16) = p;
            p.x = f2bf(acc11[0]); p.y = f2bf(acc11[1]); p.z = f2bf(acc11[2]); p.w = f2bf(acc11[3]);
            *(ushort4*)(O + (size_t)(n1 + 16 + lr) * 128 + ir0 + 16) = p;
        }
    }
    grid.sync();

    // ================= Phase D: out = relu(xTh0 - adjT@xTh1) =================
    {
        int b = bid >> 4, t16 = bid & 15;
        int j0 = (t16 >> 3) * 64, n0 = (t16 & 7) * 32;
        int w = tid >> 6, lane = tid & 63;
        int lr = lane & 15, lg = lane >> 4;
        const unsigned short* Ap  = adjTb + (size_t)b * 16384 + (size_t)(j0 + w * 16 + lr) * 128 + lg * 8;
        const unsigned short* Bp0 = xTh1T + (size_t)b * 32768 + (size_t)(n0 + lr) * 128 + lg * 8;
        const unsigned short* Bp1 = Bp0 + 16 * 128;
        f32x4 acc0 = {0.f,0.f,0.f,0.f}, acc1 = {0.f,0.f,0.f,0.f};
        #pragma unroll
        for (int ks = 0; ks < 4; ++ks) {
            bf16x8 av = *(const bf16x8*)(Ap + ks * 32);
            bf16x8 b0 = *(const bf16x8*)(Bp0 + ks * 32);
            bf16x8 b1 = *(const bf16x8*)(Bp1 + ks * 32);
            acc0 = __builtin_amdgcn_mfma_f32_16x16x32_bf16(av, b0, acc0, 0, 0, 0);
            acc1 = __builtin_amdgcn_mfma_f32_16x16x32_bf16(av, b1, acc1, 0, 0, 0);
        }
        int j = j0 + w * 16 + lg * 4;
        const float* X0 = xTh0 + (size_t)b * 32768 + (size_t)j * 256 + n0 + lr;
        float* O = out + (size_t)b * 32768 + (size_t)j * 256 + n0 + lr;
        #pragma unroll
        for (int r = 0; r < 4; ++r) {
            O[r * 256]      = fmaxf(X0[r * 256]      - acc0[r], 0.f);
            O[r * 256 + 16] = fmaxf(X0[r * 256 + 16] - acc1[r], 0.f);
        }
    }
}

extern "C" void kernel_launch(void* const* d_in, const int* in_sizes, int n_in,
                              void* d_out, int out_size, void* d_ws, size_t ws_size,
                              hipStream_t stream) {
    const float* x     = (const float*)d_in[0];   // [32,128,256]
    const float* a     = (const float*)d_in[1];   // [128,128]
    const float* Theta = (const float*)d_in[2];   // [2,256,256]
    float* out = (float*)d_out;
    float* f0  = (float*)d_ws;

    // workspace (f32 units); diff dead after B2 -> xTh1T aliases it (written in C).
    float*          diff  = f0;                               // 524288 f32
    unsigned short* xTh1T = (unsigned short*)f0;              // 1048576 bf16 (alias)
    float*          aT    = f0 + 524288;                      // 16384 f32
    float*          rnorm = f0 + 540672;                      // 16384 f32
    float*          xTh0  = f0 + 557056;                      // 1048576 f32
    unsigned short* xb    = (unsigned short*)(f0 + 1605632);  // 1048576 bf16
    unsigned short* thT   = (unsigned short*)(f0 + 2129920);  // 131072 bf16
    unsigned short* adjTb = (unsigned short*)(f0 + 2195456);  // 524288 bf16
    // total 2457600 f32 = 9.83 MB

    void* args[] = {(void*)&x, (void*)&Theta, (void*)&a, (void*)&diff, (void*)&xb,
                    (void*)&thT, (void*)&aT, (void*)&rnorm, (void*)&adjTb,
                    (void*)&xTh0, (void*)&xTh1T, (void*)&out};
    hipLaunchCooperativeKernel((const void*)k_fused, dim3(GRID), dim3(256), args, 0, stream);
}

// Round 6
// 99.554 us; speedup vs baseline: 3.3656x; 3.3656x over previous
//
#include <hip/hip_runtime.h>
#include <hip/hip_bf16.h>

// B=32, C=128, L=256, K=2. deg==1 -> L_t = -adj.
// out[b] = relu( [x[b] | y[b]] @ [Th0; Th1] ),  y[b] = -(adjT[b] @ x[b])
// K1 k_pre : pairdist(i<=j) + {xb, xbT} bf16 + thT2 (=[Th0;Th1]^T) bf16 + aT
// K2 k_mega: per (b, 16-row j-tile): adjacency -> y (MFMA) -> out (MFMA, K=512)

#define NB 32
#define NC 128
#define NL 256

typedef short bf16x8 __attribute__((ext_vector_type(8)));
typedef float f32x4 __attribute__((ext_vector_type(4)));

static __device__ __forceinline__ unsigned short f2bf(float f) {
    unsigned u = __builtin_bit_cast(unsigned, f);
    u += 0x7fff + ((u >> 16) & 1);            // RNE
    return (unsigned short)(u >> 16);
}

__device__ const unsigned char TI36[36] = {0,0,0,0,0,0,0,0, 1,1,1,1,1,1,1, 2,2,2,2,2,2,
                                           3,3,3,3,3, 4,4,4,4, 5,5,5, 6,6, 7};
__device__ const unsigned char TJ36[36] = {0,1,2,3,4,5,6,7, 1,2,3,4,5,6,7, 2,3,4,5,6,7,
                                           3,4,5,6,7, 4,5,6,7, 5,6,7, 6,7, 7};

// ---------------- K1: pairdist + conversions ----------------
// blocks [0,1152): pairdist; [1152,1408): x -> xb + xbT; [1408,1440): thT2; [1440,1444): aT
__global__ __launch_bounds__(256) void k_pre(const float* __restrict__ x,
                                             const float* __restrict__ Theta,
                                             const float* __restrict__ a,
                                             float* __restrict__ diff,
                                             unsigned short* __restrict__ xb,
                                             unsigned short* __restrict__ xbT,
                                             unsigned short* __restrict__ thT2,
                                             float* __restrict__ aT) {
    __shared__ float smem[8592];   // pairdist: xi 4160 | xj 4160 | sT 272 ; transpose: [64][65]
    int bid = blockIdx.x;
    int tid = threadIdx.x;

    if (bid < 1152) {
        int b = bid / 36, p = bid - b * 36;
        int i0 = TI36[p] * 16, j0 = TJ36[p] * 16;
        float* xi = smem;
        float* xj = smem + 4160;
        float* sT = smem + 8320;
        const float4* x4 = (const float4*)(x + (size_t)b * NC * NL);
        for (int idx = tid; idx < 16 * 64; idx += 256) {
            int r = idx >> 6, c = idx & 63;
            *(float4*)&xi[r * 260 + c * 4] = x4[(i0 + r) * 64 + c];
            *(float4*)&xj[r * 260 + c * 4] = x4[(j0 + r) * 64 + c];
        }
        __syncthreads();
        int il = tid >> 4, jl = tid & 15;
        float acc = 0.f;
        #pragma unroll 8
        for (int l4 = 0; l4 < 64; ++l4) {
            float4 u = *(const float4*)&xi[il * 260 + l4 * 4];
            float4 v = *(const float4*)&xj[jl * 260 + l4 * 4];
            acc += fabsf(u.x - v.x) + fabsf(u.y - v.y) +
                   fabsf(u.z - v.z) + fabsf(u.w - v.w);
        }
        float* D = diff + (size_t)b * NC * NC;
        D[(i0 + il) * NC + j0 + jl] = acc;        // direct, coalesced
        sT[jl * 17 + il] = acc;
        __syncthreads();
        D[(j0 + il) * NC + i0 + jl] = sT[il * 17 + jl];  // mirror via LDS transpose
    } else if (bid < 1408) {
        // x[b] 64x64 f32 tile -> xb (row-major bf16) + xbT ([l][i] bf16)
        int tt = bid - 1152;                      // (b:5, itile:1, ltile:2)
        int b = tt >> 3, rem = tt & 7;
        int i0 = (rem >> 2) * 64, l0 = (rem & 3) * 64;
        const float4* x4 = (const float4*)(x + (size_t)b * NC * NL);
        for (int idx = tid; idx < 1024; idx += 256) {
            int r = idx >> 4, c4 = idx & 15;
            *(float4*)&smem[r * 65 + c4 * 4] = x4[(i0 + r) * 64 + (l0 >> 2) + c4];
        }
        __syncthreads();
        for (int idx = tid; idx < 1024; idx += 256) {
            int r = idx >> 4, c4 = idx & 15;
            ushort4 o;   // xb[i0+r][l0 + 4*c4 ..]
            o.x = f2bf(smem[r * 65 + c4 * 4 + 0]);
            o.y = f2bf(smem[r * 65 + c4 * 4 + 1]);
            o.z = f2bf(smem[r * 65 + c4 * 4 + 2]);
            o.w = f2bf(smem[r * 65 + c4 * 4 + 3]);
            *(ushort4*)(xb + (size_t)b * 32768 + (size_t)(i0 + r) * 256 + l0 + c4 * 4) = o;
            ushort4 p;   // xbT[l0+r][i0 + 4*c4 ..]
            p.x = f2bf(smem[(c4 * 4 + 0) * 65 + r]);
            p.y = f2bf(smem[(c4 * 4 + 1) * 65 + r]);
            p.z = f2bf(smem[(c4 * 4 + 2) * 65 + r]);
            p.w = f2bf(smem[(c4 * 4 + 3) * 65 + r]);
            *(ushort4*)(xbT + (size_t)b * 32768 + (size_t)(l0 + r) * 128 + i0 + c4 * 4) = p;
        }
    } else if (bid < 1440) {
        // thT2[n][t*256 + l] = Theta[t][l][n]
        int tt = bid - 1408;
        int t = tt >> 4, rem = tt & 15;
        int l0 = (rem >> 2) * 64, n0 = (rem & 3) * 64;
        const float4* T4 = (const float4*)(Theta + (size_t)t * 65536);
        for (int idx = tid; idx < 1024; idx += 256) {
            int r = idx >> 4, c4 = idx & 15;
            *(float4*)&smem[r * 65 + c4 * 4] = T4[(l0 + r) * 64 + (n0 >> 2) + c4];
        }
        __syncthreads();
        for (int idx = tid; idx < 1024; idx += 256) {
            int r = idx >> 4, c4 = idx & 15;   // row n0+r, l-offset l0+4*c4
            ushort4 o;
            o.x = f2bf(smem[(c4 * 4 + 0) * 65 + r]);
            o.y = f2bf(smem[(c4 * 4 + 1) * 65 + r]);
            o.z = f2bf(smem[(c4 * 4 + 2) * 65 + r]);
            o.w = f2bf(smem[(c4 * 4 + 3) * 65 + r]);
            *(ushort4*)(thT2 + (size_t)(n0 + r) * 512 + t * 256 + l0 + c4 * 4) = o;
        }
    } else {
        // aT[j][i] = a[i][j]
        int tt = bid - 1440;
        int i0 = (tt >> 1) * 64, j0 = (tt & 1) * 64;
        for (int it = tid; it < 4096; it += 256) {
            int r = it >> 6, c = it & 63;
            smem[r * 65 + c] = a[(i0 + r) * NC + j0 + c];
        }
        __syncthreads();
        for (int it = tid; it < 4096; it += 256) {
            int r = it >> 6, c = it & 63;
            aT[(j0 + r) * NC + i0 + c] = smem[c * 65 + r];
        }
    }
}

// ---------------- K2: per-(b, 16-j-tile) mega kernel ----------------
// 256 blocks (b*8 + jt), 256 threads.
// Phase 1: adjacency columns j0..j0+15 -> adjL[j][i] = -adj[i][j] (bf16)
// Phase 2: yL[j][l] = adjL @ x[b]      (MFMA, B-frags from xbT)
// Phase 3: out[b][j][n] = relu( [xb[b][j][:] | yL[j][:]] @ thT2^T )
__global__ __launch_bounds__(256) void k_mega(const float* __restrict__ diff,
                                              const float* __restrict__ aT,
                                              const unsigned short* __restrict__ xb,
                                              const unsigned short* __restrict__ xbT,
                                              const unsigned short* __restrict__ thT2,
                                              float* __restrict__ out) {
    __shared__ __align__(16) short adjL[16 * 144];   // row stride 288 B
    __shared__ __align__(16) short yL[16 * 272];     // row stride 544 B
    int bid = blockIdx.x;
    int b = bid >> 3, jt = bid & 7, j0 = jt * 16;
    int tid = threadIdx.x;

    // ---- Phase 1: adjacency ----
    {
        int jl = tid >> 4, il = tid & 15;             // j = j0+jl, i = il + 16*r
        const float* Dp = diff + (size_t)(j0 + jl) * NC + il;   // diff[bb][j][i] (symmetric)
        const float* Ap = aT + (size_t)(j0 + jl) * NC + il;     // a[i][j]
        float sv[8];
        float cs = 0.f;
        #pragma unroll
        for (int r = 0; r < 8; ++r) {
            int off = 16 * r;
            float ss = 0.f;
            #pragma unroll
            for (int bb = 0; bb < NB; ++bb) {
                float v = Dp[(size_t)bb * NC * NC + off];
                ss = fmaf(v, v, ss);
            }
            float rn = 1.0f / fmaxf(sqrtf(ss), 1e-12f);
            float d  = Dp[(size_t)b * NC * NC + off];
            float av = Ap[off];
            float s = __expf(fmaxf((1.0f - d * rn) * av, 0.0f));
            sv[r] = s;
            cs += s;
        }
        cs += __shfl_xor(cs, 1); cs += __shfl_xor(cs, 2);
        cs += __shfl_xor(cs, 4); cs += __shfl_xor(cs, 8);
        float inv = -1.0f / cs;                       // fold the y negation here
        #pragma unroll
        for (int r = 0; r < 8; ++r)
            adjL[jl * 144 + il + 16 * r] = (short)f2bf(sv[r] * inv);
    }
    __syncthreads();

    int w = tid >> 6, lane = tid & 63, lr = lane & 15, lg = lane >> 4;

    // ---- Phase 2: yL = adjL @ x[b]  (M=16 j, N=256 l, K=128 i) ----
    {
        f32x4 acc[4];
        #pragma unroll
        for (int f = 0; f < 4; ++f) acc[f] = (f32x4){0.f, 0.f, 0.f, 0.f};
        const unsigned short* Bb = xbT + (size_t)b * 32768;
        #pragma unroll
        for (int ks = 0; ks < 4; ++ks) {
            bf16x8 af = *(const bf16x8*)&adjL[lr * 144 + ks * 32 + lg * 8];
            #pragma unroll
            for (int f = 0; f < 4; ++f) {
                bf16x8 bv = *(const bf16x8*)(Bb + (size_t)(w * 64 + f * 16 + lr) * 128 + ks * 32 + lg * 8);
                acc[f] = __builtin_amdgcn_mfma_f32_16x16x32_bf16(af, bv, acc[f], 0, 0, 0);
            }
        }
        #pragma unroll
        for (int f = 0; f < 4; ++f)
            #pragma unroll
            for (int r = 0; r < 4; ++r)
                yL[(lg * 4 + r) * 272 + w * 64 + f * 16 + lr] = (short)f2bf(acc[f][r]);
    }
    __syncthreads();

    // ---- Phase 3: out tile (M=16 j, N=256 n, K=512) ----
    {
        f32x4 o[4];
        #pragma unroll
        for (int f = 0; f < 4; ++f) o[f] = (f32x4){0.f, 0.f, 0.f, 0.f};
        const unsigned short* Arow = xb + (size_t)b * 32768 + (size_t)(j0 + lr) * 256;
        #pragma unroll
        for (int ks = 0; ks < 16; ++ks) {
            bf16x8 af = (ks < 8)
                ? *(const bf16x8*)(Arow + ks * 32 + lg * 8)
                : *(const bf16x8*)&yL[lr * 272 + (ks - 8) * 32 + lg * 8];
            #pragma unroll
            for (int f = 0; f < 4; ++f) {
                bf16x8 bv = *(const bf16x8*)(thT2 + (size_t)(w * 64 + f * 16 + lr) * 512 + ks * 32 + lg * 8);
                o[f] = __builtin_amdgcn_mfma_f32_16x16x32_bf16(af, bv, o[f], 0, 0, 0);
            }
        }
        float* Ob = out + (size_t)b * 32768;
        #pragma unroll
        for (int f = 0; f < 4; ++f)
            #pragma unroll
            for (int r = 0; r < 4; ++r)
                Ob[(size_t)(j0 + lg * 4 + r) * 256 + w * 64 + f * 16 + lr] = fmaxf(o[f][r], 0.f);
    }
}

extern "C" void kernel_launch(void* const* d_in, const int* in_sizes, int n_in,
                              void* d_out, int out_size, void* d_ws, size_t ws_size,
                              hipStream_t stream) {
    const float* x     = (const float*)d_in[0];   // [32,128,256]
    const float* a     = (const float*)d_in[1];   // [128,128]
    const float* Theta = (const float*)d_in[2];   // [2,256,256]
    float* out = (float*)d_out;
    float* f0  = (float*)d_ws;

    float*          diff = f0;                                // 524288 f32 (2 MB)
    float*          aT   = f0 + 524288;                       // 16384 f32
    unsigned short* xb   = (unsigned short*)(f0 + 540672);    // 1048576 bf16
    unsigned short* xbT  = (unsigned short*)(f0 + 1064960);   // 1048576 bf16
    unsigned short* thT2 = (unsigned short*)(f0 + 1589248);   // 131072 bf16
    // total 1654784 f32 = 6.62 MB

    k_pre <<<dim3(1444), dim3(256), 0, stream>>>(x, Theta, a, diff, xb, xbT, thT2, aT);
    k_mega<<<dim3(256), dim3(256), 0, stream>>>(diff, aT, xb, xbT, thT2, out);
}

// Round 7
// 94.338 us; speedup vs baseline: 3.5517x; 1.0553x over previous
//
#include <hip/hip_runtime.h>
#include <hip/hip_bf16.h>

// B=32, C=128, L=256, K=2. deg==1 -> L_t = -adj.
// out[b] = relu( [x[b] | y[b]] @ [Th0; Th1] ),  y[b] = adjN[b] @ x[b],  adjN = -adj^T (normalized)
// K1 k_pre : pairdist(i<=j) + ssum atomics + {xb, xbT} bf16 + thT2 bf16 + aT
// K2 k_adj : adjacency from ssum (no redundant norm recompute), negated, bf16 [j][i]
// K3 k_gemm: per (b, jt16, nhalf): y (MFMA) -> LDS -> out (MFMA K=512) + ReLU

#define NB 32
#define NC 128
#define NL 256

typedef short bf16x8 __attribute__((ext_vector_type(8)));
typedef float f32x4 __attribute__((ext_vector_type(4)));

static __device__ __forceinline__ unsigned short f2bf(float f) {
    unsigned u = __builtin_bit_cast(unsigned, f);
    u += 0x7fff + ((u >> 16) & 1);            // RNE
    return (unsigned short)(u >> 16);
}

__device__ const unsigned char TI36[36] = {0,0,0,0,0,0,0,0, 1,1,1,1,1,1,1, 2,2,2,2,2,2,
                                           3,3,3,3,3, 4,4,4,4, 5,5,5, 6,6, 7};
__device__ const unsigned char TJ36[36] = {0,1,2,3,4,5,6,7, 1,2,3,4,5,6,7, 2,3,4,5,6,7,
                                           3,4,5,6,7, 4,5,6,7, 5,6,7, 6,7, 7};

// ---------------- K1: pairdist (+ssum atomics) + conversions ----------------
// blocks [0,1152): pairdist; [1152,1408): x -> xb + xbT; [1408,1440): thT2; [1440,1444): aT
__global__ __launch_bounds__(256) void k_pre(const float* __restrict__ x,
                                             const float* __restrict__ Theta,
                                             const float* __restrict__ a,
                                             float* __restrict__ diff,
                                             float* __restrict__ ssum,
                                             unsigned short* __restrict__ xb,
                                             unsigned short* __restrict__ xbT,
                                             unsigned short* __restrict__ thT2,
                                             float* __restrict__ aT) {
    __shared__ float smem[8592];   // pairdist: xi 4160 | xj 4160 | sT 272 ; transpose: [64][65]
    int bid = blockIdx.x;
    int tid = threadIdx.x;

    if (bid < 1152) {
        int b = bid / 36, p = bid - b * 36;
        int i0 = TI36[p] * 16, j0 = TJ36[p] * 16;
        float* xi = smem;
        float* xj = smem + 4160;
        float* sT = smem + 8320;
        const float4* x4 = (const float4*)(x + (size_t)b * NC * NL);
        for (int idx = tid; idx < 16 * 64; idx += 256) {
            int r = idx >> 6, c = idx & 63;
            *(float4*)&xi[r * 260 + c * 4] = x4[(i0 + r) * 64 + c];
            *(float4*)&xj[r * 260 + c * 4] = x4[(j0 + r) * 64 + c];
        }
        __syncthreads();
        int il = tid >> 4, jl = tid & 15;
        float acc = 0.f;
        #pragma unroll 8
        for (int l4 = 0; l4 < 64; ++l4) {
            float4 u = *(const float4*)&xi[il * 260 + l4 * 4];
            float4 v = *(const float4*)&xj[jl * 260 + l4 * 4];
            acc += fabsf(u.x - v.x) + fabsf(u.y - v.y) +
                   fabsf(u.z - v.z) + fabsf(u.w - v.w);
        }
        float* D = diff + (size_t)b * NC * NC;
        D[(i0 + il) * NC + j0 + jl] = acc;        // direct, coalesced
        sT[jl * 17 + il] = acc;
        // batch-norm accumulator (kernel boundary = the global sync before use)
        float d2 = acc * acc;
        atomicAdd(&ssum[(i0 + il) * NC + j0 + jl], d2);
        if (i0 != j0) atomicAdd(&ssum[(j0 + jl) * NC + i0 + il], d2);
        __syncthreads();
        D[(j0 + il) * NC + i0 + jl] = sT[il * 17 + jl];  // mirror via LDS transpose
    } else if (bid < 1408) {
        // x[b] 64x64 f32 tile -> xb (row-major bf16) + xbT ([l][i] bf16)
        int tt = bid - 1152;                      // (b:5, itile:1, ltile:2)
        int b = tt >> 3, rem = tt & 7;
        int i0 = (rem >> 2) * 64, l0 = (rem & 3) * 64;
        const float4* x4 = (const float4*)(x + (size_t)b * NC * NL);
        for (int idx = tid; idx < 1024; idx += 256) {
            int r = idx >> 4, c4 = idx & 15;
            *(float4*)&smem[r * 65 + c4 * 4] = x4[(i0 + r) * 64 + (l0 >> 2) + c4];
        }
        __syncthreads();
        for (int idx = tid; idx < 1024; idx += 256) {
            int r = idx >> 4, c4 = idx & 15;
            ushort4 o;   // xb[i0+r][l0 + 4*c4 ..]
            o.x = f2bf(smem[r * 65 + c4 * 4 + 0]);
            o.y = f2bf(smem[r * 65 + c4 * 4 + 1]);
            o.z = f2bf(smem[r * 65 + c4 * 4 + 2]);
            o.w = f2bf(smem[r * 65 + c4 * 4 + 3]);
            *(ushort4*)(xb + (size_t)b * 32768 + (size_t)(i0 + r) * 256 + l0 + c4 * 4) = o;
            ushort4 p;   // xbT[l0+r][i0 + 4*c4 ..]
            p.x = f2bf(smem[(c4 * 4 + 0) * 65 + r]);
            p.y = f2bf(smem[(c4 * 4 + 1) * 65 + r]);
            p.z = f2bf(smem[(c4 * 4 + 2) * 65 + r]);
            p.w = f2bf(smem[(c4 * 4 + 3) * 65 + r]);
            *(ushort4*)(xbT + (size_t)b * 32768 + (size_t)(l0 + r) * 128 + i0 + c4 * 4) = p;
        }
    } else if (bid < 1440) {
        // thT2[n][t*256 + l] = Theta[t][l][n]
        int tt = bid - 1408;
        int t = tt >> 4, rem = tt & 15;
        int l0 = (rem >> 2) * 64, n0 = (rem & 3) * 64;
        const float4* T4 = (const float4*)(Theta + (size_t)t * 65536);
        for (int idx = tid; idx < 1024; idx += 256) {
            int r = idx >> 4, c4 = idx & 15;
            *(float4*)&smem[r * 65 + c4 * 4] = T4[(l0 + r) * 64 + (n0 >> 2) + c4];
        }
        __syncthreads();
        for (int idx = tid; idx < 1024; idx += 256) {
            int r = idx >> 4, c4 = idx & 15;   // row n0+r, l-offset l0+4*c4
            ushort4 o;
            o.x = f2bf(smem[(c4 * 4 + 0) * 65 + r]);
            o.y = f2bf(smem[(c4 * 4 + 1) * 65 + r]);
            o.z = f2bf(smem[(c4 * 4 + 2) * 65 + r]);
            o.w = f2bf(smem[(c4 * 4 + 3) * 65 + r]);
            *(ushort4*)(thT2 + (size_t)(n0 + r) * 512 + t * 256 + l0 + c4 * 4) = o;
        }
    } else {
        // aT[j][i] = a[i][j]
        int tt = bid - 1440;
        int i0 = (tt >> 1) * 64, j0 = (tt & 1) * 64;
        for (int it = tid; it < 4096; it += 256) {
            int r = it >> 6, c = it & 63;
            smem[r * 65 + c] = a[(i0 + r) * NC + j0 + c];
        }
        __syncthreads();
        for (int it = tid; it < 4096; it += 256) {
            int r = it >> 6, c = it & 63;
            aT[(j0 + r) * NC + i0 + c] = smem[c * 65 + r];
        }
    }
}

// ---------------- K2: adjacency (negated, transposed, bf16) ----------------
// 4096 blocks (b*128 + j) x 128 threads (i). rnorm from ssum (no recompute).
__global__ __launch_bounds__(128) void k_adj(const float* __restrict__ diff,
                                             const float* __restrict__ ssum,
                                             const float* __restrict__ aT,
                                             unsigned short* __restrict__ adjTb) {
    int bid = blockIdx.x;
    int b = bid >> 7, j = bid & 127;
    int i = threadIdx.x;
    float ss = ssum[j * NC + i];                  // symmetric
    float rn = 1.0f / fmaxf(sqrtf(ss), 1e-12f);
    float d  = diff[(size_t)b * NC * NC + j * NC + i];
    float av = aT[j * NC + i];
    float s = __expf(fmaxf((1.0f - d * rn) * av, 0.0f));
    float t = s;
    #pragma unroll
    for (int off = 32; off; off >>= 1) t += __shfl_xor(t, off);
    __shared__ float partial[2];
    if ((i & 63) == 0) partial[i >> 6] = t;
    __syncthreads();
    float total = partial[0] + partial[1];
    adjTb[(size_t)b * NC * NC + j * NC + i] = f2bf(-s / total);   // fold y's negation
}

// ---------------- K3: fused y = adjN@x ; out = relu([x|y] @ Th2) ----------------
// 512 blocks: b*16 + jt*2 + nh. 256 thr (4 waves). Wave w: y n-quarter w, out 2 n-frags.
__global__ __launch_bounds__(256) void k_gemm(const unsigned short* __restrict__ adjTb,
                                              const unsigned short* __restrict__ xb,
                                              const unsigned short* __restrict__ xbT,
                                              const unsigned short* __restrict__ thT2,
                                              float* __restrict__ out) {
    __shared__ __align__(16) short yL[16 * 272];     // row stride 544 B
    int bid = blockIdx.x;
    int b = bid >> 4, jt = (bid >> 1) & 7, nh = bid & 1;
    int j0 = jt * 16;
    int tid = threadIdx.x, w = tid >> 6, lane = tid & 63;
    int lr = lane & 15, lg = lane >> 4;

    // ---- Phase A: yL[16][256] = adjN_tile @ x[b]  (M=16 j, N=256 l, K=128 i) ----
    {
        f32x4 acc[4];
        #pragma unroll
        for (int f = 0; f < 4; ++f) acc[f] = (f32x4){0.f, 0.f, 0.f, 0.f};
        const unsigned short* An = adjTb + (size_t)b * 16384 + (size_t)(j0 + lr) * 128 + lg * 8;
        const unsigned short* Bb = xbT + (size_t)b * 32768;
        #pragma unroll
        for (int ks = 0; ks < 4; ++ks) {
            bf16x8 af = *(const bf16x8*)(An + ks * 32);
            #pragma unroll
            for (int f = 0; f < 4; ++f) {
                bf16x8 bv = *(const bf16x8*)(Bb + (size_t)(w * 64 + f * 16 + lr) * 128 + ks * 32 + lg * 8);
                acc[f] = __builtin_amdgcn_mfma_f32_16x16x32_bf16(af, bv, acc[f], 0, 0, 0);
            }
        }
        #pragma unroll
        for (int f = 0; f < 4; ++f)
            #pragma unroll
            for (int r = 0; r < 4; ++r)
                yL[(lg * 4 + r) * 272 + w * 64 + f * 16 + lr] = (short)f2bf(acc[f][r]);
    }
    __syncthreads();

    // ---- Phase B: out half (M=16 j, N=128, K=512) ----
    {
        f32x4 o[2];
        o[0] = (f32x4){0.f, 0.f, 0.f, 0.f};
        o[1] = (f32x4){0.f, 0.f, 0.f, 0.f};
        const unsigned short* Arow = xb + (size_t)b * 32768 + (size_t)(j0 + lr) * 256;
        #pragma unroll
        for (int ks = 0; ks < 16; ++ks) {
            bf16x8 af = (ks < 8)
                ? *(const bf16x8*)(Arow + ks * 32 + lg * 8)
                : *(const bf16x8*)&yL[lr * 272 + (ks - 8) * 32 + lg * 8];
            #pragma unroll
            for (int f = 0; f < 2; ++f) {
                int n = nh * 128 + w * 32 + f * 16 + lr;
                bf16x8 bv = *(const bf16x8*)(thT2 + (size_t)n * 512 + ks * 32 + lg * 8);
                o[f] = __builtin_amdgcn_mfma_f32_16x16x32_bf16(af, bv, o[f], 0, 0, 0);
            }
        }
        float* Ob = out + (size_t)b * 32768;
        #pragma unroll
        for (int f = 0; f < 2; ++f)
            #pragma unroll
            for (int r = 0; r < 4; ++r)
                Ob[(size_t)(j0 + lg * 4 + r) * 256 + nh * 128 + w * 32 + f * 16 + lr] =
                    fmaxf(o[f][r], 0.f);
    }
}

extern "C" void kernel_launch(void* const* d_in, const int* in_sizes, int n_in,
                              void* d_out, int out_size, void* d_ws, size_t ws_size,
                              hipStream_t stream) {
    const float* x     = (const float*)d_in[0];   // [32,128,256]
    const float* a     = (const float*)d_in[1];   // [128,128]
    const float* Theta = (const float*)d_in[2];   // [2,256,256]
    float* out = (float*)d_out;
    float* f0  = (float*)d_ws;

    float*          diff  = f0;                                // 524288 f32 (2 MB)
    float*          ssum  = f0 + 524288;                       // 16384 f32
    float*          aT    = f0 + 540672;                       // 16384 f32
    unsigned short* xb    = (unsigned short*)(f0 + 557056);    // 1048576 bf16
    unsigned short* xbT   = (unsigned short*)(f0 + 1081344);   // 1048576 bf16
    unsigned short* thT2  = (unsigned short*)(f0 + 1605632);   // 131072 bf16
    unsigned short* adjTb = (unsigned short*)(f0 + 1671168);   // 524288 bf16
    // total 1933312 f32 = 7.73 MB

    hipMemsetAsync(ssum, 0, 16384 * sizeof(float), stream);
    k_pre <<<dim3(1444), dim3(256), 0, stream>>>(x, Theta, a, diff, ssum, xb, xbT, thT2, aT);
    k_adj <<<dim3(NB * NC), dim3(128), 0, stream>>>(diff, ssum, aT, adjTb);
    k_gemm<<<dim3(512), dim3(256), 0, stream>>>(adjTb, xb, xbT, thT2, out);
}

// Round 8
// 91.405 us; speedup vs baseline: 3.6657x; 1.0321x over previous
//
#include <hip/hip_runtime.h>
#include <hip/hip_bf16.h>

// B=32, C=128, L=256, K=2. deg==1 -> L_t = -adj.
// out[b] = relu( [x[b] | y[b]] @ [Th0; Th1] ),  y[b][j] = -sum_i adj[i][j] x[i]
// K1 k_pre : pairdist (32x32 i<=j reg-blocked) + ssum atomics + {xb,xbT} + thT2 + aT
// K2 k_fuse: per (b, jt16, nhalf): adjacency(from ssum) -> y (MFMA) -> out (MFMA K=512) + ReLU

#define NB 32
#define NC 128
#define NL 256

typedef short bf16x8 __attribute__((ext_vector_type(8)));
typedef float f32x4 __attribute__((ext_vector_type(4)));

static __device__ __forceinline__ unsigned short f2bf(float f) {
    unsigned u = __builtin_bit_cast(unsigned, f);
    u += 0x7fff + ((u >> 16) & 1);            // RNE
    return (unsigned short)(u >> 16);
}

__device__ const unsigned char TI10[10] = {0,0,0,0, 1,1,1, 2,2, 3};
__device__ const unsigned char TJ10[10] = {0,1,2,3, 1,2,3, 2,3, 3};

// ---------------- K1 ----------------
// blocks [0,320): pairdist 32x32; [320,576): x->xb+xbT; [576,608): thT2; [608,612): aT
__global__ __launch_bounds__(256) void k_pre(const float* __restrict__ x,
                                             const float* __restrict__ Theta,
                                             const float* __restrict__ a,
                                             float* __restrict__ diff,
                                             float* __restrict__ ssum,
                                             unsigned short* __restrict__ xb,
                                             unsigned short* __restrict__ xbT,
                                             unsigned short* __restrict__ thT2,
                                             float* __restrict__ aT) {
    __shared__ float smem[4480];   // pairdist: xi[32][68] | xj[32][68] (sT aliases xi); transpose [64][65]
    int bid = blockIdx.x;
    int tid = threadIdx.x;

    if (bid < 320) {
        int b = bid / 10, p = bid - b * 10;
        int i0 = TI10[p] * 32, j0 = TJ10[p] * 32;
        float* xi = smem;              // [32][68]
        float* xj = smem + 2176;       // [32][68]
        const float4* x4 = (const float4*)(x + (size_t)b * NC * NL);
        int il = tid >> 4, jl = tid & 15;
        float a00 = 0.f, a01 = 0.f, a10 = 0.f, a11 = 0.f;
        #pragma unroll
        for (int q = 0; q < 4; ++q) {         // L quarters of 64 floats (16 float4)
            __syncthreads();
            #pragma unroll
            for (int k = 0; k < 2; ++k) {
                int idx = tid + k * 256;      // 512 float4 per buffer
                int r = idx >> 4, c4 = idx & 15;
                *(float4*)&xi[r * 68 + c4 * 4] = x4[(i0 + r) * 64 + q * 16 + c4];
                *(float4*)&xj[r * 68 + c4 * 4] = x4[(j0 + r) * 64 + q * 16 + c4];
            }
            __syncthreads();
            #pragma unroll
            for (int l4 = 0; l4 < 16; ++l4) {
                float4 u0 = *(const float4*)&xi[il * 68 + l4 * 4];
                float4 u1 = *(const float4*)&xi[(il + 16) * 68 + l4 * 4];
                float4 v0 = *(const float4*)&xj[jl * 68 + l4 * 4];
                float4 v1 = *(const float4*)&xj[(jl + 16) * 68 + l4 * 4];
                a00 += fabsf(u0.x-v0.x)+fabsf(u0.y-v0.y)+fabsf(u0.z-v0.z)+fabsf(u0.w-v0.w);
                a01 += fabsf(u0.x-v1.x)+fabsf(u0.y-v1.y)+fabsf(u0.z-v1.z)+fabsf(u0.w-v1.w);
                a10 += fabsf(u1.x-v0.x)+fabsf(u1.y-v0.y)+fabsf(u1.z-v0.z)+fabsf(u1.w-v0.w);
                a11 += fabsf(u1.x-v1.x)+fabsf(u1.y-v1.y)+fabsf(u1.z-v1.z)+fabsf(u1.w-v1.w);
            }
        }
        float* D = diff + (size_t)b * NC * NC;
        D[(i0 + il) * NC + j0 + jl]           = a00;
        D[(i0 + il) * NC + j0 + jl + 16]      = a01;
        D[(i0 + il + 16) * NC + j0 + jl]      = a10;
        D[(i0 + il + 16) * NC + j0 + jl + 16] = a11;
        atomicAdd(&ssum[(i0 + il) * NC + j0 + jl],           a00 * a00);
        atomicAdd(&ssum[(i0 + il) * NC + j0 + jl + 16],      a01 * a01);
        atomicAdd(&ssum[(i0 + il + 16) * NC + j0 + jl],      a10 * a10);
        atomicAdd(&ssum[(i0 + il + 16) * NC + j0 + jl + 16], a11 * a11);
        if (i0 != j0) {
            atomicAdd(&ssum[(j0 + jl) * NC + i0 + il],           a00 * a00);
            atomicAdd(&ssum[(j0 + jl + 16) * NC + i0 + il],      a01 * a01);
            atomicAdd(&ssum[(j0 + jl) * NC + i0 + il + 16],      a10 * a10);
            atomicAdd(&ssum[(j0 + jl + 16) * NC + i0 + il + 16], a11 * a11);
            float* sT = smem;          // [32][33], aliases xi (done reading)
            __syncthreads();
            sT[jl * 33 + il]             = a00;
            sT[(jl + 16) * 33 + il]      = a01;
            sT[jl * 33 + il + 16]        = a10;
            sT[(jl + 16) * 33 + il + 16] = a11;
            __syncthreads();
            #pragma unroll
            for (int k = 0; k < 4; ++k) {
                int idx = tid + k * 256;
                int r = idx >> 5, c = idx & 31;
                D[(j0 + r) * NC + i0 + c] = sT[r * 33 + c];
            }
        }
    } else if (bid < 576) {
        // x[b] 64x64 f32 tile -> xb (row-major bf16) + xbT ([l][i] bf16)
        int tt = bid - 320;                      // (b:5, itile:1, ltile:2)
        int b = tt >> 3, rem = tt & 7;
        int i0 = (rem >> 2) * 64, l0 = (rem & 3) * 64;
        const float4* x4 = (const float4*)(x + (size_t)b * NC * NL);
        for (int idx = tid; idx < 1024; idx += 256) {
            int r = idx >> 4, c4 = idx & 15;
            *(float4*)&smem[r * 65 + c4 * 4] = x4[(i0 + r) * 64 + (l0 >> 2) + c4];
        }
        __syncthreads();
        for (int idx = tid; idx < 1024; idx += 256) {
            int r = idx >> 4, c4 = idx & 15;
            ushort4 o;   // xb[i0+r][l0 + 4*c4 ..]
            o.x = f2bf(smem[r * 65 + c4 * 4 + 0]);
            o.y = f2bf(smem[r * 65 + c4 * 4 + 1]);
            o.z = f2bf(smem[r * 65 + c4 * 4 + 2]);
            o.w = f2bf(smem[r * 65 + c4 * 4 + 3]);
            *(ushort4*)(xb + (size_t)b * 32768 + (size_t)(i0 + r) * 256 + l0 + c4 * 4) = o;
            ushort4 p;   // xbT[l0+r][i0 + 4*c4 ..]
            p.x = f2bf(smem[(c4 * 4 + 0) * 65 + r]);
            p.y = f2bf(smem[(c4 * 4 + 1) * 65 + r]);
            p.z = f2bf(smem[(c4 * 4 + 2) * 65 + r]);
            p.w = f2bf(smem[(c4 * 4 + 3) * 65 + r]);
            *(ushort4*)(xbT + (size_t)b * 32768 + (size_t)(l0 + r) * 128 + i0 + c4 * 4) = p;
        }
    } else if (bid < 608) {
        // thT2[n][t*256 + l] = Theta[t][l][n]
        int tt = bid - 576;
        int t = tt >> 4, rem = tt & 15;
        int l0 = (rem >> 2) * 64, n0 = (rem & 3) * 64;
        const float4* T4 = (const float4*)(Theta + (size_t)t * 65536);
        for (int idx = tid; idx < 1024; idx += 256) {
            int r = idx >> 4, c4 = idx & 15;
            *(float4*)&smem[r * 65 + c4 * 4] = T4[(l0 + r) * 64 + (n0 >> 2) + c4];
        }
        __syncthreads();
        for (int idx = tid; idx < 1024; idx += 256) {
            int r = idx >> 4, c4 = idx & 15;   // row n0+r, l-offset l0+4*c4
            ushort4 o;
            o.x = f2bf(smem[(c4 * 4 + 0) * 65 + r]);
            o.y = f2bf(smem[(c4 * 4 + 1) * 65 + r]);
            o.z = f2bf(smem[(c4 * 4 + 2) * 65 + r]);
            o.w = f2bf(smem[(c4 * 4 + 3) * 65 + r]);
            *(ushort4*)(thT2 + (size_t)(n0 + r) * 512 + t * 256 + l0 + c4 * 4) = o;
        }
    } else {
        // aT[j][i] = a[i][j]
        int tt = bid - 608;
        int i0 = (tt >> 1) * 64, j0 = (tt & 1) * 64;
        for (int it = tid; it < 4096; it += 256) {
            int r = it >> 6, c = it & 63;
            smem[r * 65 + c] = a[(i0 + r) * NC + j0 + c];
        }
        __syncthreads();
        for (int it = tid; it < 4096; it += 256) {
            int r = it >> 6, c = it & 63;
            aT[(j0 + r) * NC + i0 + c] = smem[c * 65 + r];
        }
    }
}

// ---------------- K2: adjacency + y-GEMM + out-GEMM, fused ----------------
// 512 blocks: b*16 + jt*2 + nh. 256 thr (4 waves).
__global__ __launch_bounds__(256) void k_fuse(const float* __restrict__ diff,
                                              const float* __restrict__ ssum,
                                              const float* __restrict__ aT,
                                              const unsigned short* __restrict__ xb,
                                              const unsigned short* __restrict__ xbT,
                                              const unsigned short* __restrict__ thT2,
                                              float* __restrict__ out) {
    __shared__ __align__(16) short adjL[16 * 144];   // [j][i], row stride 288 B, negated adj^T
    __shared__ __align__(16) short yL[16 * 272];     // [j][l], row stride 544 B
    int bid = blockIdx.x;
    int b = bid >> 4, jt = (bid >> 1) & 7, nh = bid & 1;
    int j0 = jt * 16;
    int tid = threadIdx.x;

    // ---- Phase 0: adjacency for 16 j-columns ----
    {
        int jl = tid >> 4, ig = tid & 15;             // j = j0+jl, i = ig + 16*r
        const float* Dp = diff + (size_t)b * NC * NC + (size_t)(j0 + jl) * NC + ig;
        const float* Sp = ssum + (size_t)(j0 + jl) * NC + ig;    // symmetric
        const float* Ap = aT   + (size_t)(j0 + jl) * NC + ig;    // a[i][j]
        float sv[8];
        float cs = 0.f;
        #pragma unroll
        for (int r = 0; r < 8; ++r) {
            int off = 16 * r;
            float rn = 1.0f / fmaxf(sqrtf(Sp[off]), 1e-12f);
            float s = __expf(fmaxf((1.0f - Dp[off] * rn) * Ap[off], 0.0f));
            sv[r] = s;
            cs += s;
        }
        cs += __shfl_xor(cs, 1); cs += __shfl_xor(cs, 2);
        cs += __shfl_xor(cs, 4); cs += __shfl_xor(cs, 8);
        float inv = -1.0f / cs;                       // fold y's negation
        #pragma unroll
        for (int r = 0; r < 8; ++r)
            adjL[jl * 144 + ig + 16 * r] = (short)f2bf(sv[r] * inv);
    }
    __syncthreads();

    int w = tid >> 6, lane = tid & 63, lr = lane & 15, lg = lane >> 4;

    // ---- Phase A: yL[16][256] = adjL @ x[b]  (M=16 j, N=256 l, K=128 i) ----
    {
        f32x4 acc[4];
        #pragma unroll
        for (int f = 0; f < 4; ++f) acc[f] = (f32x4){0.f, 0.f, 0.f, 0.f};
        const unsigned short* Bb = xbT + (size_t)b * 32768;
        #pragma unroll
        for (int ks = 0; ks < 4; ++ks) {
            bf16x8 af = *(const bf16x8*)&adjL[lr * 144 + ks * 32 + lg * 8];
            #pragma unroll
            for (int f = 0; f < 4; ++f) {
                bf16x8 bv = *(const bf16x8*)(Bb + (size_t)(w * 64 + f * 16 + lr) * 128 + ks * 32 + lg * 8);
                acc[f] = __builtin_amdgcn_mfma_f32_16x16x32_bf16(af, bv, acc[f], 0, 0, 0);
            }
        }
        #pragma unroll
        for (int f = 0; f < 4; ++f)
            #pragma unroll
            for (int r = 0; r < 4; ++r)
                yL[(lg * 4 + r) * 272 + w * 64 + f * 16 + lr] = (short)f2bf(acc[f][r]);
    }
    __syncthreads();

    // ---- Phase B: out half (M=16 j, N=128, K=512) ----
    {
        f32x4 o[2];
        o[0] = (f32x4){0.f, 0.f, 0.f, 0.f};
        o[1] = (f32x4){0.f, 0.f, 0.f, 0.f};
        const unsigned short* Arow = xb + (size_t)b * 32768 + (size_t)(j0 + lr) * 256;
        #pragma unroll
        for (int ks = 0; ks < 16; ++ks) {
            bf16x8 af = (ks < 8)
                ? *(const bf16x8*)(Arow + ks * 32 + lg * 8)
                : *(const bf16x8*)&yL[lr * 272 + (ks - 8) * 32 + lg * 8];
            #pragma unroll
            for (int f = 0; f < 2; ++f) {
                int n = nh * 128 + w * 32 + f * 16 + lr;
                bf16x8 bv = *(const bf16x8*)(thT2 + (size_t)n * 512 + ks * 32 + lg * 8);
                o[f] = __builtin_amdgcn_mfma_f32_16x16x32_bf16(af, bv, o[f], 0, 0, 0);
            }
        }
        float* Ob = out + (size_t)b * 32768;
        #pragma unroll
        for (int f = 0; f < 2; ++f)
            #pragma unroll
            for (int r = 0; r < 4; ++r)
                Ob[(size_t)(j0 + lg * 4 + r) * 256 + nh * 128 + w * 32 + f * 16 + lr] =
                    fmaxf(o[f][r], 0.f);
    }
}

extern "C" void kernel_launch(void* const* d_in, const int* in_sizes, int n_in,
                              void* d_out, int out_size, void* d_ws, size_t ws_size,
                              hipStream_t stream) {
    const float* x     = (const float*)d_in[0];   // [32,128,256]
    const float* a     = (const float*)d_in[1];   // [128,128]
    const float* Theta = (const float*)d_in[2];   // [2,256,256]
    float* out = (float*)d_out;
    float* f0  = (float*)d_ws;

    float*          diff  = f0;                                // 524288 f32 (2 MB)
    float*          ssum  = f0 + 524288;                       // 16384 f32
    float*          aT    = f0 + 540672;                       // 16384 f32
    unsigned short* xb    = (unsigned short*)(f0 + 557056);    // 1048576 bf16
    unsigned short* xbT   = (unsigned short*)(f0 + 1081344);   // 1048576 bf16
    unsigned short* thT2  = (unsigned short*)(f0 + 1605632);   // 131072 bf16
    // total 1671168 f32 = 6.68 MB

    hipMemsetAsync(ssum, 0, 16384 * sizeof(float), stream);
    k_pre <<<dim3(612), dim3(256), 0, stream>>>(x, Theta, a, diff, ssum, xb, xbT, thT2, aT);
    k_fuse<<<dim3(512), dim3(256), 0, stream>>>(diff, ssum, aT, xb, xbT, thT2, out);
}